// Round 8
// baseline (287.832 us; speedup 1.0000x reference)
//
#include <hip/hip_runtime.h>
#include <hip/hip_fp16.h>

// CapsNet dynamic routing, B=256, P=2048, C=10, OUT=16, IN=8, 3 iters.
// uhat layout: [p][h][b][80co] fp16 (h = c-half), from R7.
// R8: k_route split into 3 P-sliced pass kernels (grid 512 = 2 blocks/CU;
// the fused per-b kernel was capped at 1 block/CU, 19% occupancy, and its
// wave-loads hit 64 distinct lines). Pass blocks own 8 b x 128 p: lanes
// read 8 consecutive b rows = 1280B contiguous. Cross-block reduce via
// global fp32 atomics into g_s; squash recomputed inline per block.
// P3 logit = u.(v1+v2) -> no logits buffer. k_uhat zeroes g_s/d_out.

#define Bn 256
#define Pn 2048
#define Cn 10
#define On 16
#define In 8
#define ROW 160
#define HROW 80
#define TPB 512

typedef _Float16 h2f __attribute__((ext_vector_type(2)));
union RowU { float4 f[2]; h2f hh2[8]; __half hh[16]; };

// ---------------- k_uhat ---------------- (R7 + XCD u-swizzle + zero init)
__global__ __launch_bounds__(256) void k_uhat(const float* __restrict__ u,
                                              const float* __restrict__ W,
                                              __half* __restrict__ uhat,
                                              float* __restrict__ gs12, // g_s1,g_s2 contiguous (81920 f)
                                              float* __restrict__ dout) {
  __shared__ __half st[4][64 * 88];
  const int x = blockIdx.x;
  const int p = ((x & 7) << 8) | (x >> 3); // p-adjacent u lines share an XCD
  const int t = threadIdx.x;
  const int w = t >> 6;
  const int lane = t & 63;
  // zero the accumulators for the pass kernels (122880 floats over 2048 blocks)
  if (t < 60) {
    const int flat = x * 60 + t;
    if (flat < 81920) gs12[flat] = 0.f;
    else dout[flat - 81920] = 0.f;
  }
  const float4* up = reinterpret_cast<const float4*>(u + ((size_t)t * Pn + p) * In);
  float4 x0 = up[0], x1 = up[1];
  const float uu[8] = {x0.x, x0.y, x0.z, x0.w, x1.x, x1.y, x1.z, x1.w};
  const float* wr = W + (size_t)p * (Cn * On * In); // uniform -> s_load

  __half* srow = &st[w][lane * 88];
  const __half* sbase = st[w];

  for (int h = 0; h < 2; ++h) {
#pragma unroll
    for (int ch = 0; ch < 10; ++ch) {
      union { float4 f; __half2 h2[4]; } ov;
#pragma unroll
      for (int j = 0; j < 4; ++j) {
        const float* w0 = wr + (h * 80 + ch * 8 + 2 * j) * 8;
        float d0 = w0[0] * uu[0], d1 = w0[8] * uu[0];
#pragma unroll
        for (int i = 1; i < 8; ++i) {
          d0 = __builtin_fmaf(w0[i], uu[i], d0);
          d1 = __builtin_fmaf(w0[8 + i], uu[i], d1);
        }
        ov.h2[j] = __floats2half2_rn(d0, d1);
      }
      *reinterpret_cast<float4*>(srow + ch * 8) = ov.f;
    }
    __half* gbase = uhat + (((size_t)p * 2 + h) * Bn + w * 64) * HROW;
#pragma unroll
    for (int i = 0; i < 10; ++i) {
      const int f = lane + 64 * i;
      const int r = f / 10;
      const int c = f - r * 10;
      float4 val = *reinterpret_cast<const float4*>(sbase + r * 88 + c * 8);
      *reinterpret_cast<float4*>(gbase + f * 8) = val;
    }
  }
}

// ---------------- pass kernels ----------------
// grid 512: bg = blk>>4 (8-b group), sl = blk&15 (128-p slice). TPB 512:
// b_loc = tid&7, h = (tid>>3)&1, pr = tid>>4 in [0,32). 4 p's per thread.
template <int PHASE>
__global__ __launch_bounds__(TPB, 2) void k_pass(const __half* __restrict__ uhat,
                                                 const float* __restrict__ gs1,
                                                 const float* __restrict__ gs2,
                                                 float* __restrict__ gout) {
  __shared__ float s_all[16][83];     // padded: bh-stride 83 words, conflict-free
  __shared__ __half2 vh[8][10][9];    // v (P2) or v1+v2 (P3); pad o2-dim
  const int bg = blockIdx.x >> 4;
  const int sl = blockIdx.x & 15;
  const int b0 = bg * 8;
  const int tid = threadIdx.x;
  const int lane = tid & 63;
  const int bl = tid & 7;
  const int h = (tid >> 3) & 1;
  const int pr = tid >> 4;

  if (PHASE >= 2 && tid < 80) { // per-block inline squash of prev s
    const int bb = tid / 10, c = tid - (tid / 10) * 10;
    const float* s1p = gs1 + (size_t)(b0 + bb) * ROW + c * On;
    float xv[16], sq = 0.f;
#pragma unroll
    for (int o = 0; o < On; ++o) { xv[o] = s1p[o]; sq += xv[o] * xv[o]; }
    float sc = (sq / (1.f + sq)) / sqrtf(sq + 1e-9f);
    float wv[16];
#pragma unroll
    for (int o = 0; o < On; ++o) wv[o] = sc * xv[o];
    if (PHASE == 3) { // add v2
      const float* s2p = gs2 + (size_t)(b0 + bb) * ROW + c * On;
      float y[16], sq2 = 0.f;
#pragma unroll
      for (int o = 0; o < On; ++o) { y[o] = s2p[o]; sq2 += y[o] * y[o]; }
      float sc2 = (sq2 / (1.f + sq2)) / sqrtf(sq2 + 1e-9f);
#pragma unroll
      for (int o = 0; o < On; ++o) wv[o] += sc2 * y[o];
    }
#pragma unroll
    for (int o2 = 0; o2 < 8; ++o2)
      vh[bb][c][o2] = __floats2half2_rn(wv[2 * o2], wv[2 * o2 + 1]);
  }
  for (int i = tid; i < 16 * 83; i += TPB) (&s_all[0][0])[i] = 0.f;
  __syncthreads();

  float acc[5][16];
#pragma unroll
  for (int kc = 0; kc < 5; ++kc)
#pragma unroll
    for (int o = 0; o < On; ++o) acc[kc][o] = 0.f;

  for (int it = 0; it < 4; ++it) {
    const int p = sl * 128 + it * 32 + pr;
    const __half* row = uhat + (((size_t)p * 2 + h) * Bn + b0 + bl) * HROW;
    RowU q[5];
#pragma unroll
    for (int kc = 0; kc < 5; ++kc) {
      q[kc].f[0] = *reinterpret_cast<const float4*>(row + kc * 16);
      q[kc].f[1] = *reinterpret_cast<const float4*>(row + kc * 16 + 8);
    }
    float cv[5];
    if (PHASE == 1) {
#pragma unroll
      for (int kc = 0; kc < 5; ++kc) cv[kc] = 1.f; // 0.1 applied at gather
    } else {
      float lg[5];
#pragma unroll
      for (int kc = 0; kc < 5; ++kc) {
        float d = 0.f;
#pragma unroll
        for (int o2 = 0; o2 < 8; ++o2) {
          h2f vv = *reinterpret_cast<const h2f*>(&vh[bl][h * 5 + kc][o2]);
          d = __builtin_amdgcn_fdot2(q[kc].hh2[o2], vv, d, false);
        }
        lg[kc] = d;
      }
      float m = lg[0];
#pragma unroll
      for (int kc = 1; kc < 5; ++kc) m = fmaxf(m, lg[kc]);
      m = fmaxf(m, __shfl_xor(m, 8, 64)); // partner = other h, same b
      float e[5], ssum = 0.f;
#pragma unroll
      for (int kc = 0; kc < 5; ++kc) { e[kc] = __expf(lg[kc] - m); ssum += e[kc]; }
      ssum += __shfl_xor(ssum, 8, 64);
      const float inv = 1.f / ssum;
#pragma unroll
      for (int kc = 0; kc < 5; ++kc) cv[kc] = e[kc] * inv;
    }
#pragma unroll
    for (int kc = 0; kc < 5; ++kc)
#pragma unroll
      for (int o = 0; o < On; ++o)
        acc[kc][o] = __builtin_fmaf(cv[kc], __half2float(q[kc].hh[o]), acc[kc][o]);
  }

  // reduce: shuffle over the 4 same-(b,h) lanes in-wave, then LDS atomics
#pragma unroll
  for (int k = 0; k < HROW; ++k) {
    float xr = acc[k >> 4][k & 15];
    xr += __shfl_xor(xr, 16, 64);
    xr += __shfl_xor(xr, 32, 64);
    if (lane < 16) atomicAdd(&s_all[lane][k], xr);
  }
  __syncthreads();
  const float scale = (PHASE == 1) ? 0.1f : 1.0f;
  for (int i = tid; i < 16 * HROW; i += TPB) {
    const int bh = i / HROW;
    const int k = i - bh * HROW;
    atomicAdd(&gout[(size_t)(b0 + (bh & 7)) * ROW + (bh >> 3) * HROW + k],
              scale * s_all[bh][k]);
  }
}

// ---------------- final squash (in-place on d_out) ----------------
__global__ __launch_bounds__(256) void k_fin(float* __restrict__ io) {
  __shared__ float s[ROW];
  __shared__ float scl[Cn];
  const int b = blockIdx.x, t = threadIdx.x;
  if (t < ROW) s[t] = io[(size_t)b * ROW + t];
  __syncthreads();
  if (t < Cn) {
    float sq = 0.f;
#pragma unroll
    for (int o = 0; o < On; ++o) { float xv = s[t * On + o]; sq += xv * xv; }
    scl[t] = (sq / (1.f + sq)) / sqrtf(sq + 1e-9f);
  }
  __syncthreads();
  if (t < ROW) io[(size_t)b * ROW + t] = s[t] * scl[t >> 4];
}

extern "C" void kernel_launch(void* const* d_in, const int* in_sizes, int n_in,
                              void* d_out, int out_size, void* d_ws, size_t ws_size,
                              hipStream_t stream) {
  (void)in_sizes; (void)n_in; (void)out_size;
  const float* u = (const float*)d_in[0];
  const float* W = (const float*)d_in[1];
  float* out = (float*)d_out;
  __half* uhat = (__half*)d_ws;
  const size_t uhat_bytes = (size_t)Bn * Pn * Cn * On * sizeof(__half); // 167.8 MB
  float* g_s1 = (float*)((char*)d_ws + uhat_bytes);
  float* g_s2 = g_s1 + (size_t)Bn * ROW;
  const size_t need = uhat_bytes + 2 * (size_t)Bn * ROW * sizeof(float);
  if (ws_size < need) return;
  k_uhat<<<Pn, 256, 0, stream>>>(u, W, uhat, g_s1, out);
  k_pass<1><<<512, TPB, 0, stream>>>(uhat, nullptr, nullptr, g_s1);
  k_pass<2><<<512, TPB, 0, stream>>>(uhat, g_s1, nullptr, g_s2);
  k_pass<3><<<512, TPB, 0, stream>>>(uhat, g_s1, g_s2, out);
  k_fin<<<Bn, 256, 0, stream>>>(out);
}